// Round 8
// baseline (396.842 us; speedup 1.0000x reference)
//
#include <hip/hip_runtime.h>
#include <hip/hip_bf16.h>
#include <cstdint>
#include <cstddef>

// ---------------------------------------------------------------------------
// MaskedSelfAttention: B=2, T=2048, C=2048, NH=16, NG=4, D=128
// sliding window 512 + sink 4, RoPE base 10000, pos 0.
// fp32 I/O; bf16 MFMA internally (fp32 accum).
// ws (32 MB): [0,16M) xb -> At ; [16,28M) Wqkvt -> Wot[16,24M)
// d_out scratch: Qb[0,16.78M), Kb[+16.78M), Vt[+20.97M) bf16 (dead at O-GEMM)
// ---------------------------------------------------------------------------

typedef short s16;
typedef short short8 __attribute__((ext_vector_type(8)));
typedef float f32x4  __attribute__((ext_vector_type(4)));

#define MFMA16(a, b, c) __builtin_amdgcn_mfma_f32_16x16x32_bf16((a), (b), (c), 0, 0, 0)

__device__ __forceinline__ float bf2f(s16 u) {
    union { float f; uint32_t i; } v;
    v.i = ((uint32_t)(uint16_t)u) << 16;
    return v.f;
}
__device__ __forceinline__ s16 f2bf(float f) {
    union { float f; uint32_t i; } v;
    v.f = f;
    uint32_t r = v.i + 0x7FFFu + ((v.i >> 16) & 1u);   // RNE
    return (s16)(r >> 16);
}

// async global->LDS, 16 B per lane of the wave; dest = uniform base + lane*16
__device__ __forceinline__ void gload16(const s16* g, s16* l) {
    __builtin_amdgcn_global_load_lds(
        (const __attribute__((address_space(1))) void*)g,
        (__attribute__((address_space(3))) void*)l, 16, 0, 0);
}

// ---------------------------------------------------------------------------
// prep: z=0 -> cast x fp32->bf16 (8 elem/thr); z=1..3 -> transpose+cast
// Wq/Wk/Wv into Wqkvt [3072][2048] (rows 0-2047 Wq^T, 2048-2559 Wk^T,
// 2560-3071 Wv^T).
// ---------------------------------------------------------------------------
__global__ __launch_bounds__(256)
void prep(const float* __restrict__ x, const float* __restrict__ Wq,
          const float* __restrict__ Wk, const float* __restrict__ Wv,
          s16* __restrict__ xb, s16* __restrict__ Wqkvt)
{
    int z = blockIdx.z;
    if (z == 0) {
        size_t i = (((size_t)blockIdx.y * 64 + blockIdx.x) * 256 + threadIdx.x) * 8;
        f32x4 f0 = *(const f32x4*)(x + i);
        f32x4 f1 = *(const f32x4*)(x + i + 4);
        short8 h;
        h[0]=f2bf(f0[0]); h[1]=f2bf(f0[1]); h[2]=f2bf(f0[2]); h[3]=f2bf(f0[3]);
        h[4]=f2bf(f1[0]); h[5]=f2bf(f1[1]); h[6]=f2bf(f1[2]); h[7]=f2bf(f1[3]);
        *(short8*)(xb + i) = h;
        return;
    }
    const float* in; s16* dst; int N;
    if (z == 1)      { in = Wq; dst = Wqkvt;                        N = 2048; }
    else if (z == 2) { in = Wk; dst = Wqkvt + (size_t)2048 * 2048;  N = 512; }
    else             { in = Wv; dst = Wqkvt + (size_t)2560 * 2048;  N = 512; }
    int n0 = blockIdx.x * 32, k0 = blockIdx.y * 32;
    if (n0 >= N) return;

    __shared__ float t[32][33];
    int tx = threadIdx.x & 31, ty = threadIdx.x >> 5;
    for (int i = 0; i < 32; i += 8)
        t[ty + i][tx] = in[(size_t)(k0 + ty + i) * N + n0 + tx];
    __syncthreads();
    for (int i = 0; i < 32; i += 8)
        dst[(size_t)(n0 + ty + i) * 2048 + k0 + tx] = f2bf(t[tx][ty + i]);
}

// ---------------------------------------------------------------------------
// Wo transpose+cast: fp32 [2048][2048] -> bf16 ^T.
// ---------------------------------------------------------------------------
__global__ __launch_bounds__(256)
void castT(const float* __restrict__ in, s16* __restrict__ out)
{
    __shared__ float t[32][33];
    int n0 = blockIdx.x * 32, k0 = blockIdx.y * 32;
    int tx = threadIdx.x & 31, ty = threadIdx.x >> 5;
    for (int i = 0; i < 32; i += 8)
        t[ty + i][tx] = in[(size_t)(k0 + ty + i) * 2048 + n0 + tx];
    __syncthreads();
    for (int i = 0; i < 32; i += 8)
        out[(size_t)(n0 + ty + i) * 2048 + k0 + tx] = f2bf(t[tx][ty + i]);
}

// ---------------------------------------------------------------------------
// GEMM: out = A[M][K] x Bt[N][K]^T + bias. Tile 128x128, BK=64 via four
// 8KB LDS tiles (each m97 [row][32] banking). 4 waves, wave = 64x64.
// MODE 0: QKV epilogue with FUSED ROPE for Q/K blocks (n0<2560); V blocks
//         (n0>=2560) store transposed to Vt. Block cols = exactly one head,
//         pairs (i,i+64) exchanged across wave pairs via LDS (reuses As).
// MODE 2: fp32 out + bias.
// mfma_f32_16x16x32_bf16 layouts (verified m89/m91):
//   A-frag: A[m=lane&15][k=(lane>>4)*8+j]; B-frag: B[k=(lane>>4)*8+j][n=lane&15]
//   C/D:    row=(lane>>4)*4+reg, col=lane&15
// ---------------------------------------------------------------------------
template <int MODE>
__global__ __launch_bounds__(256)
void gemm_lds(const s16* __restrict__ A, const s16* __restrict__ Bt,
              const float* __restrict__ b0, const float* __restrict__ b1,
              const float* __restrict__ b2,
              void* __restrict__ o0, void* __restrict__ o1, void* __restrict__ o2,
              int M, int N, int K)
{
    __shared__ s16 As[2][128 * 32];   // [k-half][row][32]
    __shared__ s16 Bs[2][128 * 32];

    const int tid  = threadIdx.x;
    const int m0   = blockIdx.x * 128, n0 = blockIdx.y * 128;
    const int lane = tid & 63, wv = tid >> 6;
    const int wm   = (wv >> 1) * 64, wn = (wv & 1) * 64;
    const int fr   = lane & 15, fq = lane >> 4;

    const int srow = wv * 16 + (lane >> 2);   // 4 lanes/row, 16 rows/wave
    const int koff = (lane & 3) * 8;
    const s16* gA0 = A  + (size_t)(m0 + srow) * K + koff;
    const s16* gA1 = A  + (size_t)(m0 + 64 + srow) * K + koff;
    const s16* gB0 = Bt + (size_t)(n0 + srow) * K + koff;
    const s16* gB1 = Bt + (size_t)(n0 + 64 + srow) * K + koff;
    s16* lA0 = &As[0][(wv * 16) * 32];
    s16* lA0h = &As[0][(64 + wv * 16) * 32];
    s16* lA1 = &As[1][(wv * 16) * 32];
    s16* lA1h = &As[1][(64 + wv * 16) * 32];
    s16* lB0 = &Bs[0][(wv * 16) * 32];
    s16* lB0h = &Bs[0][(64 + wv * 16) * 32];
    s16* lB1 = &Bs[1][(wv * 16) * 32];
    s16* lB1h = &Bs[1][(64 + wv * 16) * 32];

    f32x4 acc[4][4] = {};

    for (int k0 = 0; k0 < K; k0 += 64) {
        __syncthreads();
        gload16(gA0 + k0,      lA0);
        gload16(gA0 + k0 + 32, lA1);
        gload16(gA1 + k0,      lA0h);
        gload16(gA1 + k0 + 32, lA1h);
        gload16(gB0 + k0,      lB0);
        gload16(gB0 + k0 + 32, lB1);
        gload16(gB1 + k0,      lB0h);
        gload16(gB1 + k0 + 32, lB1h);
        __syncthreads();

        #pragma unroll
        for (int ks = 0; ks < 2; ks++) {
            short8 af[4], bfr[4];
            #pragma unroll
            for (int i = 0; i < 4; i++)
                af[i] = *(const short8*)&As[ks][(wm + i * 16 + fr) * 32 + fq * 8];
            #pragma unroll
            for (int i = 0; i < 4; i++)
                bfr[i] = *(const short8*)&Bs[ks][(wn + i * 16 + fr) * 32 + fq * 8];
            #pragma unroll
            for (int mi = 0; mi < 4; mi++)
                #pragma unroll
                for (int ni = 0; ni < 4; ni++)
                    acc[mi][ni] = MFMA16(af[mi], bfr[ni], acc[mi][ni]);
        }
    }

    if (MODE == 2) {
        #pragma unroll
        for (int mi = 0; mi < 4; mi++)
            #pragma unroll
            for (int ni = 0; ni < 4; ni++)
                #pragma unroll
                for (int r = 0; r < 4; r++) {
                    int m = m0 + wm + mi * 16 + fq * 4 + r;
                    int n = n0 + wn + ni * 16 + fr;
                    ((float*)o0)[(size_t)m * N + n] = acc[mi][ni][r] + b0[n];
                }
        return;
    }

    // MODE 0
    if (n0 >= 2560) {   // V: transposed store, no rope
        #pragma unroll
        for (int mi = 0; mi < 4; mi++)
            #pragma unroll
            for (int ni = 0; ni < 4; ni++)
                #pragma unroll
                for (int r = 0; r < 4; r++) {
                    int m = m0 + wm + mi * 16 + fq * 4 + r;
                    int n = n0 + wn + ni * 16 + fr;
                    ((s16*)o2)[(size_t)(n - 2560) * 4096 + m] =
                        f2bf(acc[mi][ni][r] + b2[n - 2560]);
                }
        return;
    }

    // Q or K block: fused RoPE. Block columns = one head's 128 dims.
    {
        float (*ex)[16][128] = (float (*)[16][128])(&As[0][0]);   // 16 KB alias
        const float* brow = (n0 < 2048) ? (b0 + n0) : (b1 + (n0 - 2048));
        const int pair = wv >> 1;
        float invf[4];
        #pragma unroll
        for (int ni = 0; ni < 4; ni++)
            invf[ni] = exp2f((float)(ni * 16 + fr) * (-0.20762050593245055f));

        #pragma unroll
        for (int mi = 0; mi < 4; mi++) {
            __syncthreads();    // also guards LDS alias vs last k-iter reads
            #pragma unroll
            for (int ni = 0; ni < 4; ni++)
                #pragma unroll
                for (int r = 0; r < 4; r++)
                    ex[pair][fq * 4 + r][wn + ni * 16 + fr] =
                        acc[mi][ni][r] + brow[wn + ni * 16 + fr];
            __syncthreads();
            #pragma unroll
            for (int ni = 0; ni < 4; ni++) {
                #pragma unroll
                for (int r = 0; r < 4; r++) {
                    int rl = fq * 4 + r;
                    float own  = ex[pair][rl][wn + ni * 16 + fr];
                    float part = ex[pair][rl][(wn ^ 64) + ni * 16 + fr];
                    int m = m0 + wm + mi * 16 + rl;
                    float ang = (float)(m & 2047) * invf[ni];
                    float sn, cs;
                    __sincosf(ang, &sn, &cs);
                    float v = (wn == 0) ? (own * cs - part * sn)
                                        : (part * sn + own * cs);
                    int n = n0 + wn + ni * 16 + fr;
                    if (n0 < 2048)
                        ((s16*)o0)[(size_t)m * 2048 + n] = f2bf(v);
                    else
                        ((s16*)o1)[(size_t)m * 512 + (n - 2048)] = f2bf(v);
                }
            }
        }
    }
}

// ---------------------------------------------------------------------------
// Flash attention, sliding window + sink; both batches (z=b). BARRIER-FREE:
// K/V fragments loaded directly global->VGPR (L2-resident working set);
// only the wave-private P layout roundtrip uses LDS (threadfence only).
// Q [4096][2048] bf16; Kb [4096][512]; Vt [512][4096]; At [2][2048][2048].
// Block 256 thr = 4 independent waves; 64 q rows of one h; key chunks of 32.
// ---------------------------------------------------------------------------
__global__ __launch_bounds__(256)
void attn_kernel(const s16* __restrict__ Q, const s16* __restrict__ Kb,
                 const s16* __restrict__ Vt, s16* __restrict__ At)
{
    __shared__ s16 Ps[4][16][40];    // per-wave P (wave-private)

    int b = blockIdx.z;
    int h = blockIdx.y, g = h >> 2;
    int t0 = (31 - blockIdx.x) * 64;          // heavy blocks dispatch first
    int tid = threadIdx.x, lane = tid & 63, wv = tid >> 6;
    int fr = lane & 15, fq = lane >> 4;
    int tw = t0 + wv * 16;
    s16* O = At + (size_t)b * 4194304;

    const float scale = 0.08838834764831845f;   // 128^-0.5
    const float NEG = -1e9f;

    const s16* Kbase = Kb + (size_t)(b * 2048) * 512 + g * 128;
    const s16* Vbase = Vt + (size_t)(g * 128) * 4096 + b * 2048;

    // Q A-frags for the whole kernel
    short8 qf[4];
    {
        const s16* qrow = Q + (size_t)(b * 2048 + tw + fr) * 2048 + h * 128 + fq * 8;
        qf[0] = *(const short8*)(qrow);
        qf[1] = *(const short8*)(qrow + 32);
        qf[2] = *(const short8*)(qrow + 64);
        qf[3] = *(const short8*)(qrow + 96);
    }

    f32x4 Oacc[8] = {};
    float m_r[4], l_r[4];
    #pragma unroll
    for (int r = 0; r < 4; r++) { m_r[r] = NEG; l_r[r] = 0.0f; }

    int lo = t0 - 512; if (lo < 0) lo = 0;
    int c0   = lo >> 5;
    int cend = (t0 + 63) >> 5;
    int nch  = cend - c0 + 1 + (c0 > 0 ? 1 : 0);

    for (int ic = 0; ic < nch; ic++) {
        int kbase = ((c0 > 0) ? (ic == 0 ? 0 : c0 + ic - 1) : ic) * 32;

        // K fragments direct from global (16 rows x 64B per frag set)
        short8 kf[2][4];
        #pragma unroll
        for (int kn = 0; kn < 2; kn++)
            #pragma unroll
            for (int dc = 0; dc < 4; dc++)
                kf[kn][dc] = *(const short8*)
                    (Kbase + (size_t)(kbase + kn * 16 + fr) * 512 + dc * 32 + fq * 8);

        // S = Q K^T
        float sv[2][4];
        #pragma unroll
        for (int kn = 0; kn < 2; kn++) {
            f32x4 sc4 = {0.f, 0.f, 0.f, 0.f};
            #pragma unroll
            for (int dc = 0; dc < 4; dc++)
                sc4 = MFMA16(qf[dc], kf[kn][dc], sc4);
            int j = kbase + kn * 16 + fr;
            #pragma unroll
            for (int r = 0; r < 4; r++) {
                int t = tw + fq * 4 + r;
                bool ok = (j <= t) && ((j >= t - 512) || (j < 4));
                sv[kn][r] = ok ? sc4[r] * scale : NEG;
            }
        }

        // online softmax; row fq*4+r lives in lanes fq*16..fq*16+15
        float alpha[4], p0[4], p1[4];
        #pragma unroll
        for (int r = 0; r < 4; r++) {
            float cm = fmaxf(sv[0][r], sv[1][r]);
            for (int off = 1; off < 16; off <<= 1)
                cm = fmaxf(cm, __shfl_xor(cm, off));
            float nm = fmaxf(m_r[r], cm);
            alpha[r] = __expf(m_r[r] - nm);
            p0[r] = __expf(sv[0][r] - nm);
            p1[r] = __expf(sv[1][r] - nm);
            float ps = p0[r] + p1[r];
            for (int off = 1; off < 16; off <<= 1)
                ps += __shfl_xor(ps, off);
            l_r[r] = l_r[r] * alpha[r] + ps;
            m_r[r] = nm;
        }
        #pragma unroll
        for (int n0 = 0; n0 < 8; n0++)
            #pragma unroll
            for (int r = 0; r < 4; r++)
                Oacc[n0][r] *= alpha[r];

        // P: C/D layout -> A layout via wave-private LDS roundtrip
        #pragma unroll
        for (int r = 0; r < 4; r++) {
            Ps[wv][fq * 4 + r][fr]      = f2bf(p0[r]);
            Ps[wv][fq * 4 + r][16 + fr] = f2bf(p1[r]);
        }
        __threadfence_block();
        short8 pf = *(const short8*)&Ps[wv][fr][fq * 8];

        // O += P V ; V fragments direct from global
        #pragma unroll
        for (int n0 = 0; n0 < 8; n0++) {
            short8 vf = *(const short8*)
                (Vbase + (size_t)(n0 * 16 + fr) * 4096 + kbase + fq * 8);
            Oacc[n0] = MFMA16(pf, vf, Oacc[n0]);
        }
    }

    float invl[4];
    #pragma unroll
    for (int r = 0; r < 4; r++) invl[r] = 1.0f / l_r[r];
    #pragma unroll
    for (int n0 = 0; n0 < 8; n0++)
        #pragma unroll
        for (int r = 0; r < 4; r++) {
            int t = tw + fq * 4 + r;
            O[(size_t)t * 2048 + h * 128 + n0 * 16 + fr] =
                f2bf(Oacc[n0][r] * invl[r]);
        }
}

// ---------------------------------------------------------------------------
// Launcher (memory map at top of file).
// ---------------------------------------------------------------------------
extern "C" void kernel_launch(void* const* d_in, const int* in_sizes, int n_in,
                              void* d_out, int out_size, void* d_ws, size_t ws_size,
                              hipStream_t stream)
{
    const float* x  = (const float*)d_in[0];
    const float* Wq = (const float*)d_in[1];
    const float* bq = (const float*)d_in[2];
    const float* Wk = (const float*)d_in[3];
    const float* bk = (const float*)d_in[4];
    const float* Wv = (const float*)d_in[5];
    const float* bv = (const float*)d_in[6];
    const float* Wo = (const float*)d_in[7];
    const float* bo = (const float*)d_in[8];
    float* out = (float*)d_out;

    if (ws_size < 33554432) return;

    char* ws = (char*)d_ws;
    s16* xb    = (s16*)(ws + 0);           // [4096][2048] bf16 (16 MB)
    s16* At    = (s16*)(ws + 0);           // [2][2048][2048] bf16 (after xb dies)
    s16* Wqkvt = (s16*)(ws + 16777216);    // [3072][2048] bf16 (12 MB)
    s16* Wot   = (s16*)(ws + 16777216);    // [2048][2048] bf16 (after QKV GEMM)
    s16* Qb    = (s16*)d_out;                              // [4096][2048] bf16
    s16* Kb    = (s16*)((char*)d_out + 16777216);          // [4096][512]  bf16
    s16* Vt    = (s16*)((char*)d_out + 20971520);          // [512][4096]  bf16

    // x cast + QKV weight transposes, one launch
    prep<<<dim3(64, 64, 4), 256, 0, stream>>>(x, Wq, Wk, Wv, xb, Wqkvt);

    // fused QKV projection + RoPE epilogue
    gemm_lds<0><<<dim3(32, 24), 256, 0, stream>>>(xb, Wqkvt, bq, bk, bv,
                                                  Qb, Kb, Vt, 4096, 3072, 2048);

    // O weight (overwrites dead Wqkvt)
    castT<<<dim3(64, 64), 256, 0, stream>>>(Wo, Wot);

    // attention, both batches (xb dead -> At reuses its space)
    attn_kernel<<<dim3(32, 16, 2), 256, 0, stream>>>(Qb, Kb, Vt, At);

    // output projection: At [4096][2048] x Wot + bo -> out fp32
    gemm_lds<2><<<dim3(32, 16), 256, 0, stream>>>(At, Wot, bo, nullptr, nullptr,
                                                  out, nullptr, nullptr,
                                                  4096, 2048, 2048);
}